// Round 9
// baseline (773.356 us; speedup 1.0000x reference)
//
#include <hip/hip_runtime.h>
#include <math.h>

// Observer recurrence -> LTI Markov-parameter convolution.
//   A' = A - L*C, K = [B - L*D | L | h0], f_m = C A'^m K
//   y_t = f_t[9] + D*u_t + sum_j f_j . z_{t-1-j};  out = 3*tanh(y)
// Round-17 (= r16 with compile fix): persistent cooperative chain with
// MANUAL coherence. r16's only failure: HIP float4 (a struct) as 128-bit
// inline-asm INPUT operand -> "indirect register inputs" error. All asm
// vector operands are now ext_vector_type (f32x4), which map to VGPR tuples.
// Evidence base unchanged: r13 (A at 4MB/XCD, null) -> launch boundaries
// wb-inv per-XCD L2s; r9 -> grid.sync fence = 75us/step. So: ONE coop
// launch, 256 blocks (1/CU), 28 steps inside.
//   - A': plain cached loads, L2-hot all steps (V-block t & R-block 128+t
//     share XCD t%8; 4MB/XCD).
//   - W/Rpart (cross-step): sc0 sc1 loads/stores (bypass L1+L2, coherent
//     at L3) -> never invalidate, never evict A.
//   - Wf/gf (read by later kernels only): nontemporal stores.
//   - barrier: per-step arrival counter, relaxed device-scope atomics +
//     s_sleep spin; 28 slots, no reuse.
// V-role: 128 blocks x 2 tiles, live-B (80KB) staged to LDS per step.
// R-role: r6's VALU matvec. Math identical to r6 -> absmax ~0.0352.

constexpr int NDIM  = 4096;
constexpr int NC    = 10;         // live columns of K/W
constexpr int SLAB  = 16 * 4096;  // padded 16-col col-major slab (elements)
constexpr int JT    = 56;         // truncation length
constexpr int VAPPS = 28;         // V-chain applications (W_1..W_28)
constexpr int KC    = NDIM / 32;  // 128 k-chunks of 32
constexpr int TILES = NDIM / 16;  // 256 row-tiles of 16
constexpr size_t RPN = (size_t)128 * NDIM;  // one Rpart buffer (elements)

typedef float    f32x4  __attribute__((ext_vector_type(4)));
typedef _Float16 h16x8  __attribute__((ext_vector_type(8)));
typedef _Float16 f16;

// ---------- build A' = A - L*C, fp16, swizzled to fragment order ----------
__global__ __launch_bounds__(256) void k_build_a(
        const float* __restrict__ A, const float* __restrict__ C,
        const float* __restrict__ L, h16x8* __restrict__ AhSw) {
    __shared__ float lds[64][65];
    const int R0 = (blockIdx.x & 63) * 64;
    const int C0 = (blockIdx.x >> 6) * 64;
    const int tid = threadIdx.x;
    #pragma unroll
    for (int it = 0; it < 16; ++it) {
        const int r = it * 4 + (tid >> 6);
        const int c = tid & 63;
        lds[r][c] = A[(size_t)(R0 + r) * NDIM + C0 + c]
                  - L[R0 + r] * C[C0 + c];
    }
    __syncthreads();
    #pragma unroll
    for (int half = 0; half < 2; ++half) {
        const int o = half * 256 + tid;
        const int r = o >> 3;
        const int g = o & 7;
        union { h16x8 v; f16 h[8]; } pk;
        #pragma unroll
        for (int j = 0; j < 8; ++j) pk.h[j] = (f16)lds[r][g * 8 + j];
        const int tile = (R0 >> 4) + (r >> 4);
        const int kc   = (C0 >> 5) + (g >> 2);
        const int lane = (r & 15) | ((g & 3) << 4);
        AhSw[((size_t)tile * KC + kc) * 64 + lane] = pk.v;
    }
}

// ---------- W0 = K, fp32 + fp16; zero barrier flags ----------
__global__ __launch_bounds__(256) void k_build_w0(
        const float* __restrict__ Bm, const float* __restrict__ Dm,
        const float* __restrict__ L,
        float* __restrict__ Wf, f16* __restrict__ Wh,
        unsigned int* __restrict__ flags) {
    int k = blockIdx.x * blockDim.x + threadIdx.x; // < 4096
    if (k < 64) flags[k] = 0u;
    float Lk = L[k];
    float col[16];
    #pragma unroll
    for (int c = 0; c < 8; ++c) col[c] = Bm[k * 8 + c] - Lk * Dm[c];
    col[8] = Lk; col[9] = 1.0f;
    #pragma unroll
    for (int c = 10; c < 16; ++c) col[c] = 0.0f;
    #pragma unroll
    for (int c = 0; c < 16; ++c) {
        Wf[c * NDIM + k] = col[c];
        Wh[c * NDIM + k] = (f16)col[c];
    }
}

// ---------- persistent chain ----------
__global__ __launch_bounds__(256, 1) void k_persist(
        const h16x8* __restrict__ AhSw, f16* __restrict__ WhB,
        float* __restrict__ Wf, const float* __restrict__ Cvec,
        float* __restrict__ gf, float* __restrict__ Rpart,
        unsigned int* __restrict__ flags) {
    __shared__ f16   Bst[10][4104];   // 82 KB: live-B, full K
    __shared__ f32x4 red[4][64];
    __shared__ float rp[128][36];
    __shared__ float g8v[8][33];
    __shared__ float gs[32];
    const int tid  = threadIdx.x;
    const int bid  = blockIdx.x;
    const int lane = tid & 63, wave = tid >> 6;
    const int mr   = lane & 15, q = lane >> 4;

    if (bid < 128) {
        // ================= V role: tiles 2b, 2b+1 =================
        const int tp = bid;
        const int tile = tp * 2 + (wave >> 1);
        const int kh   = wave & 1;
        const bool liveB = (mr < NC);
        const h16x8* a8 = AhSw + ((size_t)tile * KC + (size_t)kh * 64) * 64 + lane;
        const f16* bl = &Bst[0][0] + (size_t)mr * 4104 + kh * 2048 + q * 8;

        for (int r = 0; r < VAPPS; ++r) {
            // ---- stage live-B (80 KB) to LDS: 20 sc-loads per thread ----
            {
                const f16* p = WhB + (size_t)r * SLAB + (size_t)tid * 160;
                f32x4 b0,b1,b2,b3,b4,b5,b6,b7,b8,b9,b10,b11,b12,b13,b14,b15,b16,b17,b18,b19;
                asm volatile(
                    "global_load_dwordx4 %0, %20, off sc0 sc1\n\t"
                    "global_load_dwordx4 %1, %20, off offset:16 sc0 sc1\n\t"
                    "global_load_dwordx4 %2, %20, off offset:32 sc0 sc1\n\t"
                    "global_load_dwordx4 %3, %20, off offset:48 sc0 sc1\n\t"
                    "global_load_dwordx4 %4, %20, off offset:64 sc0 sc1\n\t"
                    "global_load_dwordx4 %5, %20, off offset:80 sc0 sc1\n\t"
                    "global_load_dwordx4 %6, %20, off offset:96 sc0 sc1\n\t"
                    "global_load_dwordx4 %7, %20, off offset:112 sc0 sc1\n\t"
                    "global_load_dwordx4 %8, %20, off offset:128 sc0 sc1\n\t"
                    "global_load_dwordx4 %9, %20, off offset:144 sc0 sc1\n\t"
                    "global_load_dwordx4 %10, %20, off offset:160 sc0 sc1\n\t"
                    "global_load_dwordx4 %11, %20, off offset:176 sc0 sc1\n\t"
                    "global_load_dwordx4 %12, %20, off offset:192 sc0 sc1\n\t"
                    "global_load_dwordx4 %13, %20, off offset:208 sc0 sc1\n\t"
                    "global_load_dwordx4 %14, %20, off offset:224 sc0 sc1\n\t"
                    "global_load_dwordx4 %15, %20, off offset:240 sc0 sc1\n\t"
                    "global_load_dwordx4 %16, %20, off offset:256 sc0 sc1\n\t"
                    "global_load_dwordx4 %17, %20, off offset:272 sc0 sc1\n\t"
                    "global_load_dwordx4 %18, %20, off offset:288 sc0 sc1\n\t"
                    "global_load_dwordx4 %19, %20, off offset:304 sc0 sc1\n\t"
                    "s_waitcnt vmcnt(0)"
                    : "=&v"(b0),"=&v"(b1),"=&v"(b2),"=&v"(b3),"=&v"(b4),
                      "=&v"(b5),"=&v"(b6),"=&v"(b7),"=&v"(b8),"=&v"(b9),
                      "=&v"(b10),"=&v"(b11),"=&v"(b12),"=&v"(b13),"=&v"(b14),
                      "=&v"(b15),"=&v"(b16),"=&v"(b17),"=&v"(b18),"=&v"(b19)
                    : "v"(p) : "memory");
                f32x4 bb[20] = {b0,b1,b2,b3,b4,b5,b6,b7,b8,b9,b10,b11,
                                b12,b13,b14,b15,b16,b17,b18,b19};
                const int u0 = tid * 20;
                #pragma unroll
                for (int i = 0; i < 20; ++i) {
                    const int u = u0 + i;
                    union { f32x4 f; h16x8 h; } cv; cv.f = bb[i];
                    *(h16x8*)&Bst[u >> 9][(u & 511) * 8] = cv.h;
                }
            }
            __syncthreads();

            // ---- MFMA: W_{r+1} tile ----
            f32x4 acc0 = {0,0,0,0}, acc1 = {0,0,0,0};
            for (int it = 0; it < 8; ++it) {
                h16x8 ra[8], rb[8];
                #pragma unroll
                for (int s = 0; s < 8; ++s) rb[s] = (h16x8){0,0,0,0,0,0,0,0};
                #pragma unroll
                for (int s = 0; s < 8; ++s) ra[s] = a8[(size_t)(it * 8 + s) * 64];
                if (liveB) {
                    #pragma unroll
                    for (int s = 0; s < 8; ++s)
                        rb[s] = *(const h16x8*)(bl + (it * 8 + s) * 32);
                }
                #pragma unroll
                for (int s = 0; s < 8; ++s) {
                    if (s & 1) acc1 = __builtin_amdgcn_mfma_f32_16x16x32_f16(ra[s], rb[s], acc1, 0, 0, 0);
                    else       acc0 = __builtin_amdgcn_mfma_f32_16x16x32_f16(ra[s], rb[s], acc0, 0, 0, 0);
                }
            }
            red[wave][lane] = acc0 + acc1;
            __syncthreads();
            if (tid < 128) {
                const int half = tid >> 6, l = tid & 63;
                f32x4 v = red[half * 2][l] + red[half * 2 + 1][l];
                const int col = l & 15;
                if (col < NC) {
                    const int rb0 = (tp * 2 + half) * 16 + ((l >> 4) << 2);
                    float* wf = Wf + (size_t)(r + 1) * SLAB + (size_t)col * NDIM + rb0;
                    #pragma unroll
                    for (int i = 0; i < 4; ++i)
                        __builtin_nontemporal_store(v[i], wf + i);
                    union { f16 h[4]; int2 u2; } pk;
                    #pragma unroll
                    for (int i = 0; i < 4; ++i) pk.h[i] = (f16)v[i];
                    f16* wh = WhB + (size_t)(r + 1) * SLAB + (size_t)col * NDIM + rb0;
                    asm volatile("global_store_dwordx2 %0, %1, off sc0 sc1"
                                 :: "v"(wh), "v"(pk.u2) : "memory");
                }
            }
            // ---- barrier ----
            asm volatile("s_waitcnt vmcnt(0)" ::: "memory");
            __syncthreads();
            if (tid == 0) {
                __hip_atomic_fetch_add(&flags[r], 1u, __ATOMIC_RELAXED, __HIP_MEMORY_SCOPE_AGENT);
                while (__hip_atomic_load(&flags[r], __ATOMIC_RELAXED, __HIP_MEMORY_SCOPE_AGENT) < 256u)
                    __builtin_amdgcn_s_sleep(2);
            }
            __syncthreads();
        }
    } else {
        // ================= R role: rows [32t, 32t+32) =================
        const int t = bid - 128;
        for (int r = 0; r < VAPPS; ++r) {
            if (r == 0) {
                if (tid < 32) gs[tid] = Cvec[t * 32 + tid];
                __syncthreads();
            } else {
                const float* RpIn = Rpart + (size_t)((r + 1) & 1) * RPN;
                const int p = tid >> 1, c0 = (tid & 1) * 16;
                const float* q4 = RpIn + (size_t)p * NDIM + t * 32 + c0;
                f32x4 v0, v1, v2, v3;
                asm volatile(
                    "global_load_dwordx4 %0, %4, off sc0 sc1\n\t"
                    "global_load_dwordx4 %1, %4, off offset:16 sc0 sc1\n\t"
                    "global_load_dwordx4 %2, %4, off offset:32 sc0 sc1\n\t"
                    "global_load_dwordx4 %3, %4, off offset:48 sc0 sc1\n\t"
                    "s_waitcnt vmcnt(0)"
                    : "=&v"(v0), "=&v"(v1), "=&v"(v2), "=&v"(v3)
                    : "v"(q4) : "memory");
                *(f32x4*)&rp[p][c0]      = v0;
                *(f32x4*)&rp[p][c0 + 4]  = v1;
                *(f32x4*)&rp[p][c0 + 8]  = v2;
                *(f32x4*)&rp[p][c0 + 12] = v3;
                __syncthreads();
                {
                    const int c = tid & 31, g = tid >> 5;
                    float s = 0.0f;
                    #pragma unroll
                    for (int j = 0; j < 16; ++j) s += rp[g * 16 + j][c];
                    g8v[g][c] = s;
                }
                __syncthreads();
                if (tid < 32) {
                    float s = 0.0f;
                    #pragma unroll
                    for (int g = 0; g < 8; ++g) s += g8v[g][tid];
                    gs[tid] = s;
                }
                __syncthreads();
            }
            if (tid < 32)
                __builtin_nontemporal_store(gs[tid], gf + (size_t)r * NDIM + t * 32 + tid);

            if (r < VAPPS - 1) {
                float gl[32];
                #pragma unroll
                for (int j = 0; j < 32; ++j) gl[j] = gs[j];
                float* RpOut = Rpart + (size_t)(r & 1) * RPN + (size_t)t * NDIM;
                #pragma unroll
                for (int cc = 0; cc < 2; ++cc) {
                    const int ch = tid * 2 + cc;        // cols [8ch, 8ch+8)
                    float acc[8] = {};
                    #pragma unroll
                    for (int tt = 0; tt < 2; ++tt) {
                        const h16x8* fr = AhSw + (size_t)(t * 2 + tt) * (KC * 64)
                                        + (size_t)ch * 16;
                        #pragma unroll
                        for (int mrr = 0; mrr < 16; ++mrr) {
                            union { h16x8 v; f16 h[8]; } ua;
                            ua.v = fr[mrr];
                            const float gm = gl[tt * 16 + mrr];
                            #pragma unroll
                            for (int j = 0; j < 8; ++j) acc[j] += gm * (float)ua.h[j];
                        }
                    }
                    f32x4 o0 = {acc[0], acc[1], acc[2], acc[3]};
                    f32x4 o1 = {acc[4], acc[5], acc[6], acc[7]};
                    float* op = RpOut + 8 * ch;
                    asm volatile(
                        "global_store_dwordx4 %0, %2, off sc0 sc1\n\t"
                        "global_store_dwordx4 %1, %3, off sc0 sc1"
                        :: "v"(op), "v"(op + 4), "v"(o0), "v"(o1) : "memory");
                }
            }
            // ---- barrier ----
            asm volatile("s_waitcnt vmcnt(0)" ::: "memory");
            __syncthreads();
            if (tid == 0) {
                __hip_atomic_fetch_add(&flags[r], 1u, __ATOMIC_RELAXED, __HIP_MEMORY_SCOPE_AGENT);
                while (__hip_atomic_load(&flags[r], __ATOMIC_RELAXED, __HIP_MEMORY_SCOPE_AGENT) < 256u)
                    __builtin_amdgcn_s_sleep(2);
            }
            __syncthreads();
        }
    }
}

// ---------- f_m for all m: m<=28 via C.W_m, m=28+i via g_i.W_28 ----------
__global__ __launch_bounds__(256) void k_fbatch(
        const float* __restrict__ Wall, const float* __restrict__ C,
        const float* __restrict__ gf, float* __restrict__ F) {
    const int m = blockIdx.x;             // 0..JT-1
    const float* W;
    const float* vec;
    if (m <= VAPPS) { W = Wall + (size_t)m * SLAB;     vec = C; }
    else            { W = Wall + (size_t)VAPPS * SLAB; vec = gf + (size_t)(m - VAPPS) * NDIM; }
    const int tid = threadIdx.x, lane = tid & 63, wave = tid >> 6;
    float acc[NC] = {};
    for (int k = tid; k < NDIM; k += 256) {
        float ck = vec[k];
        #pragma unroll
        for (int c = 0; c < NC; ++c) acc[c] += ck * W[c * NDIM + k];
    }
    __shared__ float red[4][NC];
    #pragma unroll
    for (int c = 0; c < NC; ++c) {
        float s = acc[c];
        #pragma unroll
        for (int off = 32; off > 0; off >>= 1) s += __shfl_down(s, off);
        if (lane == 0) red[wave][c] = s;
    }
    __syncthreads();
    if (tid < NC) F[m * NC + tid] = red[0][tid] + red[1][tid] + red[2][tid] + red[3][tid];
}

// ---------- causal convolution + tanh epilogue ----------
__global__ __launch_bounds__(256) void k_conv(
        const float* __restrict__ F, const float* __restrict__ u,
        const float* __restrict__ yobs, const float* __restrict__ Dm,
        float* __restrict__ out) {
    __shared__ float Fl[JT * NC];
    __shared__ float zw[(JT + 256) * 9];
    const int tid = threadIdx.x;
    const int t0  = blockIdx.x * 256;
    for (int idx = tid; idx < JT * NC; idx += 256) Fl[idx] = F[idx];
    for (int idx = tid; idx < (JT + 256) * 9; idx += 256) {
        int k = idx / 9, c = idx - k * 9;
        int s = t0 - JT + k;
        float v = 0.0f;
        if (s >= 0 && s < NDIM) v = (c < 8) ? u[c * NDIM + s] : yobs[s];
        zw[idx] = v;
    }
    __syncthreads();
    const int t = t0 + tid;
    float y = (t < JT) ? Fl[t * NC + 9] : 0.0f; // C A'^t h0 term (truncated)
    #pragma unroll
    for (int c = 0; c < 8; ++c) y += Dm[c] * u[c * NDIM + t];
    for (int j = 0; j < JT; ++j) { // s = t-1-j; s<0 hits zero pad
        const float* fj = Fl + j * NC;
        const float* zz = zw + (tid + JT - 1 - j) * 9;
        float p = 0.0f;
        #pragma unroll
        for (int c = 0; c < 9; ++c) p += fj[c] * zz[c];
        y += p;
    }
    out[t] = 3.0f * tanhf(y);
}

extern "C" void kernel_launch(void* const* d_in, const int* in_sizes, int n_in,
                              void* d_out, int out_size, void* d_ws, size_t ws_size,
                              hipStream_t stream) {
    const float* u    = (const float*)d_in[0];
    const float* yobs = (const float*)d_in[1];
    const float* A    = (const float*)d_in[2];
    const float* Bm   = (const float*)d_in[3];
    const float* C    = (const float*)d_in[4];
    const float* Dm   = (const float*)d_in[5];
    const float* L    = (const float*)d_in[6];
    float* out = (float*)d_out;

    // workspace layout (~50 MB)
    char* ws = (char*)d_ws;
    h16x8*        AhSw  = (h16x8*)ws;                     // 32 MB
    float*        Wf    = (float*)(ws + 33554432ull);     // 29*256 KB
    f16*          Wh    = (f16*)(ws + 41156608ull);       // 29*128 KB
    float*        gf    = (float*)(ws + 44957696ull);     // 28*16 KB
    float*        Rpart = (float*)(ws + 45416448ull);     // 2 * 2 MB (ping-pong)
    float*        F     = (float*)(ws + 49610752ull);     // 2.24 KB
    unsigned int* flags = (unsigned int*)(ws + 49614848ull); // 28 barrier slots

    k_build_a<<<dim3(64 * 64), dim3(256), 0, stream>>>(A, C, L, AhSw);
    k_build_w0<<<dim3(16), dim3(256), 0, stream>>>(Bm, Dm, L, Wf, Wh, flags);

    {
        void* args[] = { (void*)&AhSw, (void*)&Wh, (void*)&Wf, (void*)&C,
                         (void*)&gf, (void*)&Rpart, (void*)&flags };
        (void)hipLaunchCooperativeKernel((const void*)k_persist, dim3(256), dim3(256),
                                         args, 0u, stream);
    }

    k_fbatch<<<dim3(JT), dim3(256), 0, stream>>>(Wf, C, gf, F);
    k_conv<<<dim3(16), dim3(256), 0, stream>>>(F, u, yobs, Dm, out);
}

// Round 11
// 535.310 us; speedup vs baseline: 1.4447x; 1.4447x over previous
//
#include <hip/hip_runtime.h>
#include <math.h>

// Observer recurrence -> LTI Markov-parameter convolution.
//   A' = A - L*C, K = [B - L*D | L | h0], f_m = C A'^m K
//   y_t = f_t[9] + D*u_t + sum_j f_j . z_{t-1-j};  out = 3*tanh(y)
// Round-19: r10's int8-A failed accuracy (absmax 0.082 = 0.0352 base +
// ~0.047 chain-amplified quant noise). Same structure, 12-BIT A instead:
// per fragment 8B hi (signed, (q+8)>>4) + 4B of 8 lo-nibbles;
// q = 16*hi + nib - 8, |q| <= 2039, sA = rowmax/2039. 16x finer than int8
// -> predicted +~0.003 noise. Reconstruct to integer-valued fp16 (exact,
// |q| < 2048), the SAME validated fp16 MFMA vs fp16 W, per-row scale
// applied once in the epilogue (constant along k). R-role reads the same
// 12-bit arrays, sA folded into its g-preload.
// A-bytes 32 -> 24 MB per role; requests/step ~80 -> ~64 MB.
// Predicted: 462 -> ~375-400 us, absmax ~0.038. Revert to r6 if >0.06.

constexpr int NDIM  = 4096;
constexpr int NC    = 10;         // live columns of K/W
constexpr int SLAB  = 16 * 4096;  // padded 16-col col-major slab (elements)
constexpr int JT    = 56;         // truncation length
constexpr int VAPPS = 28;         // V-chain applications (W_1..W_28)
constexpr int KC    = NDIM / 32;  // 128 k-chunks of 32
constexpr int TILES = NDIM / 16;  // 256 row-tiles of 16

typedef float    f32x4  __attribute__((ext_vector_type(4)));
typedef _Float16 h16x8  __attribute__((ext_vector_type(8)));
typedef _Float16 f16;

// ---------- build A' = A - L*C, fp16 staging, swizzled; + per-row |max| ----
// AhSwH element (h16x8): idx = (tile*KC + kc)*64 + lane
//   lane = mr + 16q holds A'[tile*16+mr][kc*32 + q*8 .. +7]
__global__ __launch_bounds__(256) void k_build_a(
        const float* __restrict__ A, const float* __restrict__ C,
        const float* __restrict__ L, h16x8* __restrict__ AhSwH,
        unsigned int* __restrict__ rowmaxU) {
    __shared__ float lds[64][65];
    const int R0 = (blockIdx.x & 63) * 64;
    const int C0 = (blockIdx.x >> 6) * 64;
    const int tid = threadIdx.x;
    #pragma unroll
    for (int it = 0; it < 16; ++it) {
        const int r = it * 4 + (tid >> 6);
        const int c = tid & 63;
        lds[r][c] = A[(size_t)(R0 + r) * NDIM + C0 + c]
                  - L[R0 + r] * C[C0 + c];
    }
    __syncthreads();
    if (tid < 64) {
        float mx = 0.0f;
        #pragma unroll 8
        for (int c = 0; c < 64; ++c) mx = fmaxf(mx, fabsf(lds[tid][c]));
        atomicMax(&rowmaxU[R0 + tid], __float_as_uint(mx));
    }
    #pragma unroll
    for (int half = 0; half < 2; ++half) {
        const int o = half * 256 + tid;
        const int r = o >> 3;
        const int g = o & 7;
        union { h16x8 v; f16 h[8]; } pk;
        #pragma unroll
        for (int j = 0; j < 8; ++j) pk.h[j] = (f16)lds[r][g * 8 + j];
        const int tile = (R0 >> 4) + (r >> 4);
        const int kc   = (C0 >> 5) + (g >> 2);
        const int lane = (r & 15) | ((g & 3) << 4);
        AhSwH[((size_t)tile * KC + kc) * 64 + lane] = pk.v;
    }
}

// ---------- quantize A' fragments to 12-bit (per-row scale), emit sA -------
// q = clamp(round(x * 2039/rowmax), +-2039); hi = (q+8)>>4 (int8);
// nib = q - 16*hi + 8 in [0,15], packed 8 nibbles -> uint32.
__global__ __launch_bounds__(256) void k_quant_a(
        const h16x8* __restrict__ AhSwH, const unsigned int* __restrict__ rowmaxU,
        long* __restrict__ A8, unsigned int* __restrict__ A4,
        float* __restrict__ sA) {
    const size_t idx = (size_t)blockIdx.x * blockDim.x + threadIdx.x; // < TILES*KC*64
    const int lane = (int)(idx & 63);
    const int mr   = lane & 15;
    const int tile = (int)(idx >> 13);
    const int row  = tile * 16 + mr;
    const float rm  = __uint_as_float(rowmaxU[row]);
    const float inv = rm > 0.0f ? 2039.0f / rm : 0.0f;
    union { h16x8 v; f16 h[8]; } uh;
    uh.v = AhSwH[idx];
    union { long l; signed char c[8]; } uo;
    unsigned int lo = 0u;
    #pragma unroll
    for (int j = 0; j < 8; ++j) {
        int qv = (int)rintf((float)uh.h[j] * inv);
        qv = qv > 2039 ? 2039 : (qv < -2039 ? -2039 : qv);
        const int hi  = (qv + 8) >> 4;          // [-127, 127]
        const int nib = qv - (hi << 4) + 8;     // [0, 15]
        uo.c[j] = (signed char)hi;
        lo |= (unsigned int)nib << (4 * j);
    }
    A8[idx] = uo.l;
    A4[idx] = lo;
    if (((idx >> 6) & (KC - 1)) == 0 && (lane >> 4) == 0)
        sA[row] = rm / 2039.0f;
}

// ---------- W0 = K = [B-L*D | L | ones | 0-pad], fp32 + fp16; zero rowmax --
__global__ __launch_bounds__(256) void k_build_w0(
        const float* __restrict__ Bm, const float* __restrict__ Dm,
        const float* __restrict__ L,
        float* __restrict__ Wf, f16* __restrict__ Wh,
        unsigned int* __restrict__ rowmaxU) {
    int k = blockIdx.x * blockDim.x + threadIdx.x; // < 4096
    rowmaxU[k] = 0u;
    float Lk = L[k];
    float col[16];
    #pragma unroll
    for (int c = 0; c < 8; ++c) col[c] = Bm[k * 8 + c] - Lk * Dm[c];
    col[8] = Lk; col[9] = 1.0f;
    #pragma unroll
    for (int c = 10; c < 16; ++c) col[c] = 0.0f;
    #pragma unroll
    for (int c = 0; c < 16; ++c) {
        Wf[c * NDIM + k] = col[c];
        Wh[c * NDIM + k] = (f16)col[c];
    }
}

// ---------- fused step: V-role (blocks 0..127) + R-role (blocks 128..255) --
// V: block tp owns tiles 2tp,2tp+1; wave w: tile 2tp+(w>>1), k-half (w&1).
//    12-bit A -> integer-valued fp16 (exact), fp16 MFMA vs fp16 W frags;
//    epilogue applies sA[row].
// R: block t owns rows [32t,32t+32): reduce 128 partials, emit g_r slice,
//    next partials from the SAME 12-bit fragments (sA folded into g).
__global__ __launch_bounds__(256) void k_stepVR(
        const long* __restrict__ A8, const unsigned int* __restrict__ A4,
        const float* __restrict__ sA, const f16* __restrict__ WhIn,
        float* __restrict__ WfOut, f16* __restrict__ WhOut,
        const float* __restrict__ Cvec,
        const float* __restrict__ RpartIn, float* __restrict__ RpartOut,
        float* __restrict__ gfSlot, const int r) {
    const int tid = threadIdx.x;

    if (blockIdx.x < 128) {
        // ---------------- V role ----------------
        __shared__ f32x4 red[4][64];
        const int lane = tid & 63, wave = tid >> 6;
        const int mr   = lane & 15, q = lane >> 4;
        const int tp   = blockIdx.x;
        const int tile = tp * 2 + (wave >> 1);
        const int kh   = wave & 1;
        const int k0   = kh * 2048;
        const bool liveB = (mr < NC);
        const size_t abase = ((size_t)tile * KC + (size_t)kh * 64) * 64 + lane;
        const long*         a8 = A8 + abase;
        const unsigned int* a4 = A4 + abase;
        const h16x8* b8 = (const h16x8*)WhIn + (((size_t)mr * NDIM + k0) >> 3) + q;

        f32x4 acc0 = {0,0,0,0}, acc1 = {0,0,0,0};
        for (int it = 0; it < 8; ++it) {
            long ral[8]; unsigned int rln[8]; h16x8 rb[8];
            #pragma unroll
            for (int s = 0; s < 8; ++s) rb[s] = (h16x8){0,0,0,0,0,0,0,0};
            #pragma unroll
            for (int s = 0; s < 8; ++s) {
                ral[s] = a8[(size_t)(it * 8 + s) * 64];
                rln[s] = a4[(size_t)(it * 8 + s) * 64];
            }
            if (liveB) {
                #pragma unroll
                for (int s = 0; s < 8; ++s)
                    rb[s] = b8[(it * 8 + s) * 4];
            }
            #pragma unroll
            for (int s = 0; s < 8; ++s) {
                union { long l; signed char c[8]; } ua;
                ua.l = ral[s];
                const unsigned int lo = rln[s];
                h16x8 af;
                #pragma unroll
                for (int j = 0; j < 8; ++j) {
                    const int qv = ((int)ua.c[j] << 4)
                                 + (int)((lo >> (4 * j)) & 15u) - 8;
                    af[j] = (f16)(float)qv;
                }
                if (s & 1) acc1 = __builtin_amdgcn_mfma_f32_16x16x32_f16(af, rb[s], acc1, 0, 0, 0);
                else       acc0 = __builtin_amdgcn_mfma_f32_16x16x32_f16(af, rb[s], acc0, 0, 0, 0);
            }
        }
        red[wave][lane] = acc0 + acc1;
        __syncthreads();
        if (tid < 128) {
            const int half = tid >> 6, l = tid & 63;
            f32x4 v = red[half * 2][l] + red[half * 2 + 1][l];
            const int col = l & 15;
            if (col < NC) {
                const int rb0 = (tp * 2 + half) * 16 + ((l >> 4) << 2);
                #pragma unroll
                for (int i = 0; i < 4; ++i) {
                    const float vv = v[i] * sA[rb0 + i];
                    WfOut[col * NDIM + rb0 + i] = vv;
                    WhOut[col * NDIM + rb0 + i] = (f16)vv;
                }
            }
        }
    } else {
        // ---------------- R role ----------------
        __shared__ float rp[4096];      // [partial 128][col 32], 16 KB
        __shared__ float g8[8][33];
        __shared__ float gs[32];
        const int t = blockIdx.x - 128;  // rows [32t, 32t+32)

        if (r == 0) {
            if (tid < 32) gs[tid] = Cvec[t * 32 + tid];
        } else {
            #pragma unroll
            for (int i = 0; i < 16; ++i) {
                const int idx = tid + i * 256;
                rp[idx] = RpartIn[(size_t)(idx >> 5) * NDIM + t * 32 + (idx & 31)];
            }
            __syncthreads();
            {
                const int c = tid & 31, g = tid >> 5;   // 8 groups x 32 cols
                float s = 0.0f;
                #pragma unroll
                for (int j = 0; j < 16; ++j) s += rp[(g * 16 + j) * 32 + c];
                g8[g][c] = s;
            }
            __syncthreads();
            if (tid < 32) {
                float s = 0.0f;
                #pragma unroll
                for (int g = 0; g < 8; ++g) s += g8[g][tid];
                gs[tid] = s;
            }
        }
        __syncthreads();
        if (tid < 32) gfSlot[t * 32 + tid] = gs[tid];

        if (r < VAPPS - 1) {
            float gl[32];
            #pragma unroll
            for (int j = 0; j < 32; ++j) gl[j] = gs[j] * sA[t * 32 + j];
            #pragma unroll
            for (int cc = 0; cc < 2; ++cc) {
                const int ch = tid * 2 + cc;            // 0..511, cols [8ch,8ch+8)
                float acc[8] = {};
                #pragma unroll
                for (int tt = 0; tt < 2; ++tt) {
                    const size_t fb = (size_t)(t * 2 + tt) * (KC * 64)
                                    + (size_t)ch * 16;
                    const long*         fr8 = A8 + fb;
                    const unsigned int* fr4 = A4 + fb;
                    #pragma unroll
                    for (int mrr = 0; mrr < 16; ++mrr) {
                        union { long l; signed char c[8]; } ua;
                        ua.l = fr8[mrr];
                        const unsigned int lo = fr4[mrr];
                        const float gm = gl[tt * 16 + mrr];
                        #pragma unroll
                        for (int j = 0; j < 8; ++j) {
                            const int qv = ((int)ua.c[j] << 4)
                                         + (int)((lo >> (4 * j)) & 15u) - 8;
                            acc[j] += gm * (float)qv;
                        }
                    }
                }
                float4* op = (float4*)(RpartOut + (size_t)t * NDIM + 8 * ch);
                op[0] = make_float4(acc[0], acc[1], acc[2], acc[3]);
                op[1] = make_float4(acc[4], acc[5], acc[6], acc[7]);
            }
        }
    }
}

// ---------- f_m for all m: m<=28 via C.W_m, m=28+i via g_i.W_28 ----------
__global__ __launch_bounds__(256) void k_fbatch(
        const float* __restrict__ Wall, const float* __restrict__ C,
        const float* __restrict__ gf, float* __restrict__ F) {
    const int m = blockIdx.x;             // 0..JT-1
    const float* W;
    const float* vec;
    if (m <= VAPPS) { W = Wall + (size_t)m * SLAB;     vec = C; }
    else            { W = Wall + (size_t)VAPPS * SLAB; vec = gf + (size_t)(m - VAPPS) * NDIM; }
    const int tid = threadIdx.x, lane = tid & 63, wave = tid >> 6;
    float acc[NC] = {};
    for (int k = tid; k < NDIM; k += 256) {
        float ck = vec[k];
        #pragma unroll
        for (int c = 0; c < NC; ++c) acc[c] += ck * W[c * NDIM + k];
    }
    __shared__ float red[4][NC];
    #pragma unroll
    for (int c = 0; c < NC; ++c) {
        float s = acc[c];
        #pragma unroll
        for (int off = 32; off > 0; off >>= 1) s += __shfl_down(s, off);
        if (lane == 0) red[wave][c] = s;
    }
    __syncthreads();
    if (tid < NC) F[m * NC + tid] = red[0][tid] + red[1][tid] + red[2][tid] + red[3][tid];
}

// ---------- causal convolution + tanh epilogue ----------
__global__ __launch_bounds__(256) void k_conv(
        const float* __restrict__ F, const float* __restrict__ u,
        const float* __restrict__ yobs, const float* __restrict__ Dm,
        float* __restrict__ out) {
    __shared__ float Fl[JT * NC];
    __shared__ float zw[(JT + 256) * 9];
    const int tid = threadIdx.x;
    const int t0  = blockIdx.x * 256;
    for (int idx = tid; idx < JT * NC; idx += 256) Fl[idx] = F[idx];
    for (int idx = tid; idx < (JT + 256) * 9; idx += 256) {
        int k = idx / 9, c = idx - k * 9;
        int s = t0 - JT + k;
        float v = 0.0f;
        if (s >= 0 && s < NDIM) v = (c < 8) ? u[c * NDIM + s] : yobs[s];
        zw[idx] = v;
    }
    __syncthreads();
    const int t = t0 + tid;
    float y = (t < JT) ? Fl[t * NC + 9] : 0.0f; // C A'^t h0 term (truncated)
    #pragma unroll
    for (int c = 0; c < 8; ++c) y += Dm[c] * u[c * NDIM + t];
    for (int j = 0; j < JT; ++j) { // s = t-1-j; s<0 hits zero pad
        const float* fj = Fl + j * NC;
        const float* zz = zw + (tid + JT - 1 - j) * 9;
        float p = 0.0f;
        #pragma unroll
        for (int c = 0; c < 9; ++c) p += fj[c] * zz[c];
        y += p;
    }
    out[t] = 3.0f * tanhf(y);
}

extern "C" void kernel_launch(void* const* d_in, const int* in_sizes, int n_in,
                              void* d_out, int out_size, void* d_ws, size_t ws_size,
                              hipStream_t stream) {
    const float* u    = (const float*)d_in[0];
    const float* yobs = (const float*)d_in[1];
    const float* A    = (const float*)d_in[2];
    const float* Bm   = (const float*)d_in[3];
    const float* C    = (const float*)d_in[4];
    const float* Dm   = (const float*)d_in[5];
    const float* L    = (const float*)d_in[6];
    float* out = (float*)d_out;

    // workspace layout (~75 MB)
    char* ws = (char*)d_ws;
    h16x8*        AhSwH   = (h16x8*)ws;                       // 32 MB (staging)
    long*         A8      = (long*)(ws + 33554432ull);        // 16 MB (12-bit hi)
    unsigned int* A4      = (unsigned int*)(ws + 50331648ull);// 8 MB (12-bit lo)
    float*        Wf      = (float*)(ws + 58720256ull);       // 29*256 KB
    f16*          Wh      = (f16*)(ws + 66322432ull);         // 29*128 KB
    float*        gf      = (float*)(ws + 70123520ull);       // 28*16 KB
    float*        Rpart   = (float*)(ws + 70582272ull);       // 2*2 MB (ping-pong)
    float*        F       = (float*)(ws + 74776576ull);       // 2.24 KB
    float*        sA      = (float*)(ws + 74780672ull);       // 16 KB
    unsigned int* rowmaxU = (unsigned int*)(ws + 74797056ull);// 16 KB

    constexpr size_t RPN = (size_t)128 * NDIM;   // one Rpart buffer (elements)

    k_build_w0<<<dim3(16), dim3(256), 0, stream>>>(Bm, Dm, L, Wf, Wh, rowmaxU);
    k_build_a<<<dim3(64 * 64), dim3(256), 0, stream>>>(A, C, L, AhSwH, rowmaxU);
    k_quant_a<<<dim3(TILES * KC * 64 / 256), dim3(256), 0, stream>>>(AhSwH, rowmaxU, A8, A4, sA);

    for (int r = 0; r < VAPPS; ++r) {
        const size_t in   = (size_t)r * SLAB;
        const size_t out_ = (size_t)(r + 1) * SLAB;
        const float* rin  = Rpart + ((r + 1) & 1) * RPN;
        float*       rout = Rpart + (r & 1) * RPN;
        k_stepVR<<<dim3(256), dim3(256), 0, stream>>>(
            A8, A4, sA, Wh + in, Wf + out_, Wh + out_,
            C, rin, rout, gf + (size_t)r * NDIM, r);
    }

    k_fbatch<<<dim3(JT), dim3(256), 0, stream>>>(Wf, C, gf, F);
    k_conv<<<dim3(16), dim3(256), 0, stream>>>(F, u, yobs, Dm, out);
}

// Round 12
// 438.811 us; speedup vs baseline: 1.7624x; 1.2199x over previous
//
#include <hip/hip_runtime.h>
#include <math.h>

// Observer recurrence -> LTI Markov-parameter convolution.
//   A' = A - L*C, K = [B - L*D | L | h0], f_m = C A'^m K
//   y_t = f_t[9] + D*u_t + sum_j f_j . z_{t-1-j};  out = 3*tanh(y)
// Round-20: V-role back to r6's fp16 path (r11 post-mortem: 12-bit unpack
// on the MFMA-feed critical path cost more than its byte saving; absmax
// was bit-identical -> quant noise invisible). int8 ONLY for the R-chain's
// A-copy, plain row-major:
//  - R already pays a per-element cvt (f16->f32); i8 unpack is the same
//    cost -> free. A-R bytes 32 -> 16 MB/step.
//  - error enters only the fp32 g-vector chain (no matrix-power
//    compounding, r10's failure mode absent): tail f_29..55 get ~1-2%.
//  - plain layout: thread reads 16 contiguous bytes/row -> 4KB/instr
//    per block (swizzled R-read was an 8-16B-per-256B scatter).
// V: 128 blocks x 2 tiles, fp16 MFMA, dead-col skip (r6 exact).
// R: 128 blocks x 32 rows, int8 matvec, 16 cols/thread, fp32 carry.
// Predicted: 462 -> ~415-430 us, absmax 0.036-0.042 (threshold 0.06).

constexpr int NDIM  = 4096;
constexpr int NC    = 10;         // live columns of K/W
constexpr int SLAB  = 16 * 4096;  // padded 16-col col-major slab (elements)
constexpr int JT    = 56;         // truncation length
constexpr int VAPPS = 28;         // V-chain applications (W_1..W_28)
constexpr int KC    = NDIM / 32;  // 128 k-chunks of 32
constexpr int TILES = NDIM / 16;  // 256 row-tiles of 16

typedef float    f32x4  __attribute__((ext_vector_type(4)));
typedef _Float16 h16x8  __attribute__((ext_vector_type(8)));
typedef _Float16 f16;

// ---------- build A' = A - L*C, fp16, swizzled; + per-row |max| ----------
// AhSw element (h16x8): idx = (tile*KC + kc)*64 + lane
//   lane = mr + 16q holds A'[tile*16+mr][kc*32 + q*8 .. +7]
__global__ __launch_bounds__(256) void k_build_a(
        const float* __restrict__ A, const float* __restrict__ C,
        const float* __restrict__ L, h16x8* __restrict__ AhSw,
        unsigned int* __restrict__ rowmaxU) {
    __shared__ float lds[64][65];
    const int R0 = (blockIdx.x & 63) * 64;
    const int C0 = (blockIdx.x >> 6) * 64;
    const int tid = threadIdx.x;
    #pragma unroll
    for (int it = 0; it < 16; ++it) {
        const int r = it * 4 + (tid >> 6);
        const int c = tid & 63;
        lds[r][c] = A[(size_t)(R0 + r) * NDIM + C0 + c]
                  - L[R0 + r] * C[C0 + c];
    }
    __syncthreads();
    if (tid < 64) {
        float mx = 0.0f;
        #pragma unroll 8
        for (int c = 0; c < 64; ++c) mx = fmaxf(mx, fabsf(lds[tid][c]));
        atomicMax(&rowmaxU[R0 + tid], __float_as_uint(mx));
    }
    #pragma unroll
    for (int half = 0; half < 2; ++half) {
        const int o = half * 256 + tid;
        const int r = o >> 3;
        const int g = o & 7;
        union { h16x8 v; f16 h[8]; } pk;
        #pragma unroll
        for (int j = 0; j < 8; ++j) pk.h[j] = (f16)lds[r][g * 8 + j];
        const int tile = (R0 >> 4) + (r >> 4);
        const int kc   = (C0 >> 5) + (g >> 2);
        const int lane = (r & 15) | ((g & 3) << 4);
        AhSw[((size_t)tile * KC + kc) * 64 + lane] = pk.v;
    }
}

// ---------- quantize A' to int8 PLAIN row-major (R-chain copy) ----------
__global__ __launch_bounds__(256) void k_quant_r(
        const h16x8* __restrict__ AhSw, const unsigned int* __restrict__ rowmaxU,
        signed char* __restrict__ A8r, float* __restrict__ sAr) {
    const size_t idx = (size_t)blockIdx.x * blockDim.x + threadIdx.x; // < TILES*KC*64
    const int lane = (int)(idx & 63);
    const int kc   = (int)((idx >> 6) & (KC - 1));
    const int tile = (int)(idx >> 13);
    const int row  = tile * 16 + (lane & 15);
    const int col  = kc * 32 + (lane >> 4) * 8;
    const float rm  = __uint_as_float(rowmaxU[row]);
    const float inv = rm > 0.0f ? 127.0f / rm : 0.0f;
    union { h16x8 v; f16 h[8]; } uh;
    uh.v = AhSw[idx];
    union { long l; signed char c[8]; } uo;
    #pragma unroll
    for (int j = 0; j < 8; ++j) {
        int qv = (int)rintf((float)uh.h[j] * inv);
        qv = qv > 127 ? 127 : (qv < -127 ? -127 : qv);
        uo.c[j] = (signed char)qv;
    }
    *(long*)(A8r + (size_t)row * NDIM + col) = uo.l;
    if (kc == 0 && (lane >> 4) == 0) sAr[row] = rm / 127.0f;
}

// ---------- W0 = K = [B-L*D | L | ones | 0-pad], fp32 + fp16; zero rowmax --
__global__ __launch_bounds__(256) void k_build_w0(
        const float* __restrict__ Bm, const float* __restrict__ Dm,
        const float* __restrict__ L,
        float* __restrict__ Wf, f16* __restrict__ Wh,
        unsigned int* __restrict__ rowmaxU) {
    int k = blockIdx.x * blockDim.x + threadIdx.x; // < 4096
    rowmaxU[k] = 0u;
    float Lk = L[k];
    float col[16];
    #pragma unroll
    for (int c = 0; c < 8; ++c) col[c] = Bm[k * 8 + c] - Lk * Dm[c];
    col[8] = Lk; col[9] = 1.0f;
    #pragma unroll
    for (int c = 10; c < 16; ++c) col[c] = 0.0f;
    #pragma unroll
    for (int c = 0; c < 16; ++c) {
        Wf[c * NDIM + k] = col[c];
        Wh[c * NDIM + k] = (f16)col[c];
    }
}

// ---------- fused step: V-role (blocks 0..127) + R-role (blocks 128..255) --
// V: block tp owns tiles 2tp,2tp+1; wave w: tile 2tp+(w>>1), k-half (w&1);
//    fp16 MFMA, dead-col skip (r6 exact).
// R: block t owns rows [32t,32t+32): reduce 128 partials, emit g_r slice,
//    next partials from int8 plain A8r (sAr folded into g-preload),
//    16 cols/thread, contiguous 16B loads per row.
__global__ __launch_bounds__(256) void k_stepVR(
        const h16x8* __restrict__ AhSw,
        const signed char* __restrict__ A8r, const float* __restrict__ sAr,
        const f16* __restrict__ WhIn,
        float* __restrict__ WfOut, f16* __restrict__ WhOut,
        const float* __restrict__ Cvec,
        const float* __restrict__ RpartIn, float* __restrict__ RpartOut,
        float* __restrict__ gfSlot, const int r) {
    const int tid = threadIdx.x;

    if (blockIdx.x < 128) {
        // ---------------- V role ----------------
        __shared__ f32x4 red[4][64];
        const int lane = tid & 63, wave = tid >> 6;
        const int mr   = lane & 15, q = lane >> 4;
        const int tp   = blockIdx.x;
        const int tile = tp * 2 + (wave >> 1);
        const int kh   = wave & 1;
        const int k0   = kh * 2048;
        const bool liveB = (mr < NC);
        const h16x8* a8 = AhSw + ((size_t)tile * KC + (size_t)kh * 64) * 64 + lane;
        const h16x8* b8 = (const h16x8*)WhIn + (((size_t)mr * NDIM + k0) >> 3) + q;

        f32x4 acc0 = {0,0,0,0}, acc1 = {0,0,0,0};
        for (int it = 0; it < 8; ++it) {
            h16x8 ra[8], rb[8];
            #pragma unroll
            for (int s = 0; s < 8; ++s) rb[s] = (h16x8){0,0,0,0,0,0,0,0};
            #pragma unroll
            for (int s = 0; s < 8; ++s) {
                const int c = it * 8 + s;           // kc-local 0..63
                ra[s] = a8[(size_t)c * 64];
            }
            if (liveB) {
                #pragma unroll
                for (int s = 0; s < 8; ++s) {
                    const int c = it * 8 + s;
                    rb[s] = b8[c * 4];
                }
            }
            #pragma unroll
            for (int s = 0; s < 8; ++s) {
                if (s & 1) acc1 = __builtin_amdgcn_mfma_f32_16x16x32_f16(ra[s], rb[s], acc1, 0, 0, 0);
                else       acc0 = __builtin_amdgcn_mfma_f32_16x16x32_f16(ra[s], rb[s], acc0, 0, 0, 0);
            }
        }
        red[wave][lane] = acc0 + acc1;
        __syncthreads();
        if (tid < 128) {
            const int half = tid >> 6;          // 0: tile 2tp, 1: tile 2tp+1
            const int l    = tid & 63;
            f32x4 v = red[half * 2][l] + red[half * 2 + 1][l];
            const int col = l & 15;
            if (col < NC) {
                const int row0 = (tp * 2 + half) * 16;
                const int rb0  = row0 + ((l >> 4) << 2);
                #pragma unroll
                for (int i = 0; i < 4; ++i) {
                    WfOut[col * NDIM + rb0 + i] = v[i];
                    WhOut[col * NDIM + rb0 + i] = (f16)v[i];
                }
            }
        }
    } else {
        // ---------------- R role ----------------
        __shared__ float rp[4096];      // [partial 128][col 32], 16 KB
        __shared__ float g8[8][33];
        __shared__ float gs[32];
        const int t = blockIdx.x - 128;  // rows [32t, 32t+32)

        if (r == 0) {
            if (tid < 32) gs[tid] = Cvec[t * 32 + tid];
        } else {
            #pragma unroll
            for (int i = 0; i < 16; ++i) {
                const int idx = tid + i * 256;
                rp[idx] = RpartIn[(size_t)(idx >> 5) * NDIM + t * 32 + (idx & 31)];
            }
            __syncthreads();
            {
                const int c = tid & 31, g = tid >> 5;   // 8 groups x 32 cols
                float s = 0.0f;
                #pragma unroll
                for (int j = 0; j < 16; ++j) s += rp[(g * 16 + j) * 32 + c];
                g8[g][c] = s;
            }
            __syncthreads();
            if (tid < 32) {
                float s = 0.0f;
                #pragma unroll
                for (int g = 0; g < 8; ++g) s += g8[g][tid];
                gs[tid] = s;
            }
        }
        __syncthreads();
        if (tid < 32) gfSlot[t * 32 + tid] = gs[tid];

        if (r < VAPPS - 1) {
            float gl[32];
            #pragma unroll
            for (int j = 0; j < 32; ++j) gl[j] = gs[j] * sAr[t * 32 + j];
            const int c0 = tid * 16;            // 16 cols per thread
            float acc[16] = {};
            const int4* arow = (const int4*)(A8r + (size_t)(t * 32) * NDIM + c0);
            for (int rr = 0; rr < 32; ++rr) {
                const int4 v = arow[(size_t)rr * (NDIM / 16)];
                const float gm = gl[rr];
                const int w0 = v.x, w1 = v.y, w2 = v.z, w3 = v.w;
                #pragma unroll
                for (int b = 0; b < 4; ++b) {
                    acc[b]      += gm * (float)((w0 << (24 - 8 * b)) >> 24);
                    acc[4 + b]  += gm * (float)((w1 << (24 - 8 * b)) >> 24);
                    acc[8 + b]  += gm * (float)((w2 << (24 - 8 * b)) >> 24);
                    acc[12 + b] += gm * (float)((w3 << (24 - 8 * b)) >> 24);
                }
            }
            float4* op = (float4*)(RpartOut + (size_t)t * NDIM + c0);
            op[0] = make_float4(acc[0],  acc[1],  acc[2],  acc[3]);
            op[1] = make_float4(acc[4],  acc[5],  acc[6],  acc[7]);
            op[2] = make_float4(acc[8],  acc[9],  acc[10], acc[11]);
            op[3] = make_float4(acc[12], acc[13], acc[14], acc[15]);
        }
    }
}

// ---------- f_m for all m: m<=28 via C.W_m, m=28+i via g_i.W_28 ----------
__global__ __launch_bounds__(256) void k_fbatch(
        const float* __restrict__ Wall, const float* __restrict__ C,
        const float* __restrict__ gf, float* __restrict__ F) {
    const int m = blockIdx.x;             // 0..JT-1
    const float* W;
    const float* vec;
    if (m <= VAPPS) { W = Wall + (size_t)m * SLAB;     vec = C; }
    else            { W = Wall + (size_t)VAPPS * SLAB; vec = gf + (size_t)(m - VAPPS) * NDIM; }
    const int tid = threadIdx.x, lane = tid & 63, wave = tid >> 6;
    float acc[NC] = {};
    for (int k = tid; k < NDIM; k += 256) {
        float ck = vec[k];
        #pragma unroll
        for (int c = 0; c < NC; ++c) acc[c] += ck * W[c * NDIM + k];
    }
    __shared__ float red[4][NC];
    #pragma unroll
    for (int c = 0; c < NC; ++c) {
        float s = acc[c];
        #pragma unroll
        for (int off = 32; off > 0; off >>= 1) s += __shfl_down(s, off);
        if (lane == 0) red[wave][c] = s;
    }
    __syncthreads();
    if (tid < NC) F[m * NC + tid] = red[0][tid] + red[1][tid] + red[2][tid] + red[3][tid];
}

// ---------- causal convolution + tanh epilogue ----------
__global__ __launch_bounds__(256) void k_conv(
        const float* __restrict__ F, const float* __restrict__ u,
        const float* __restrict__ yobs, const float* __restrict__ Dm,
        float* __restrict__ out) {
    __shared__ float Fl[JT * NC];
    __shared__ float zw[(JT + 256) * 9];
    const int tid = threadIdx.x;
    const int t0  = blockIdx.x * 256;
    for (int idx = tid; idx < JT * NC; idx += 256) Fl[idx] = F[idx];
    for (int idx = tid; idx < (JT + 256) * 9; idx += 256) {
        int k = idx / 9, c = idx - k * 9;
        int s = t0 - JT + k;
        float v = 0.0f;
        if (s >= 0 && s < NDIM) v = (c < 8) ? u[c * NDIM + s] : yobs[s];
        zw[idx] = v;
    }
    __syncthreads();
    const int t = t0 + tid;
    float y = (t < JT) ? Fl[t * NC + 9] : 0.0f; // C A'^t h0 term (truncated)
    #pragma unroll
    for (int c = 0; c < 8; ++c) y += Dm[c] * u[c * NDIM + t];
    for (int j = 0; j < JT; ++j) { // s = t-1-j; s<0 hits zero pad
        const float* fj = Fl + j * NC;
        const float* zz = zw + (tid + JT - 1 - j) * 9;
        float p = 0.0f;
        #pragma unroll
        for (int c = 0; c < 9; ++c) p += fj[c] * zz[c];
        y += p;
    }
    out[t] = 3.0f * tanhf(y);
}

extern "C" void kernel_launch(void* const* d_in, const int* in_sizes, int n_in,
                              void* d_out, int out_size, void* d_ws, size_t ws_size,
                              hipStream_t stream) {
    const float* u    = (const float*)d_in[0];
    const float* yobs = (const float*)d_in[1];
    const float* A    = (const float*)d_in[2];
    const float* Bm   = (const float*)d_in[3];
    const float* C    = (const float*)d_in[4];
    const float* Dm   = (const float*)d_in[5];
    const float* L    = (const float*)d_in[6];
    float* out = (float*)d_out;

    // workspace layout (~63.4 MB)
    char* ws = (char*)d_ws;
    h16x8*        AhSw    = (h16x8*)ws;                       // 32 MB
    signed char*  A8r     = (signed char*)(ws + 33554432ull); // 16 MB
    float*        Wf      = (float*)(ws + 50331648ull);       // 29*256 KB
    f16*          Wh      = (f16*)(ws + 57933824ull);         // 29*128 KB
    float*        gf      = (float*)(ws + 61734912ull);       // 28*16 KB
    float*        Rpart   = (float*)(ws + 62193664ull);       // 2*2 MB (ping-pong)
    float*        F       = (float*)(ws + 66387968ull);       // 2.24 KB
    float*        sAr     = (float*)(ws + 66390208ull);       // 16 KB
    unsigned int* rowmaxU = (unsigned int*)(ws + 66406592ull);// 16 KB

    constexpr size_t RPN = (size_t)128 * NDIM;   // one Rpart buffer (elements)

    k_build_w0<<<dim3(16), dim3(256), 0, stream>>>(Bm, Dm, L, Wf, Wh, rowmaxU);
    k_build_a<<<dim3(64 * 64), dim3(256), 0, stream>>>(A, C, L, AhSw, rowmaxU);
    k_quant_r<<<dim3(TILES * KC * 64 / 256), dim3(256), 0, stream>>>(AhSw, rowmaxU, A8r, sAr);

    for (int r = 0; r < VAPPS; ++r) {
        const size_t in   = (size_t)r * SLAB;
        const size_t out_ = (size_t)(r + 1) * SLAB;
        const float* rin  = Rpart + ((r + 1) & 1) * RPN;
        float*       rout = Rpart + (r & 1) * RPN;
        k_stepVR<<<dim3(256), dim3(256), 0, stream>>>(
            AhSw, A8r, sAr, Wh + in, Wf + out_, Wh + out_,
            C, rin, rout, gf + (size_t)r * NDIM, r);
    }

    k_fbatch<<<dim3(JT), dim3(256), 0, stream>>>(Wf, C, gf, F);
    k_conv<<<dim3(16), dim3(256), 0, stream>>>(F, u, yobs, Dm, out);
}

// Round 13
// 425.865 us; speedup vs baseline: 1.8160x; 1.0304x over previous
//
#include <hip/hip_runtime.h>
#include <math.h>

// Observer recurrence -> LTI Markov-parameter convolution.
//   A' = A - L*C, K = [B - L*D | L | h0], f_m = C A'^m K
//   y_t = f_t[9] + D*u_t + sum_j f_j . z_{t-1-j};  out = 3*tanh(y)
// Round-21: safe byte/launch cuts on the r12 structure (V fp16 MFMA chain +
// R int8 matvec chain, MITM 28+27). r12 post-mortem fit: step time ~ 8.5us
// fixed + bytes/14TBps -> launches dominate; 28 is the 2-chain minimum.
//  (1) quantization fused into k_build_a with per-(row x 64col-group)
//      scales (finer than r12's row scales; no global rowmax pass; kills
//      the 48 MB quant_r kernel + one launch).
//  (2) Rpart carried fp16 (4 -> 2 MB/step; 0.05% partial rounding <<
//      the int8-A 0.45%/step already invisible in r12).
//  (3) Wf dropped; fbatch reads fp16 Wh (same rounding the chain itself
//      consumes; f_m +-0.05%).
// V/R inner loops untouched from r12. Predicted 439 -> ~420, absmax ~0.035.
// If >=435: fixed-cost floor confirmed -> declare structure roofline.

constexpr int NDIM  = 4096;
constexpr int NC    = 10;         // live columns of K/W
constexpr int SLAB  = 16 * 4096;  // padded 16-col col-major slab (elements)
constexpr int JT    = 56;         // truncation length
constexpr int VAPPS = 28;         // V-chain applications (W_1..W_28)
constexpr int KC    = NDIM / 32;  // 128 k-chunks of 32
constexpr int TILES = NDIM / 16;  // 256 row-tiles of 16

typedef float    f32x4  __attribute__((ext_vector_type(4)));
typedef _Float16 h16x8  __attribute__((ext_vector_type(8)));
typedef _Float16 f16;

// ---------- build A' = A - L*C: fp16 swizzled frags + int8 plain + scales --
// AhSw element (h16x8): idx = (tile*KC + kc)*64 + lane
//   lane = mr + 16q holds A'[tile*16+mr][kc*32 + q*8 .. +7]
// A8r: plain row-major int8, q = round(x * 127 / groupmax(row, 64-col blk))
// sAg[row][g]: groupmax/127 for col-group g (64 cols).
__global__ __launch_bounds__(256) void k_build_a(
        const float* __restrict__ A, const float* __restrict__ C,
        const float* __restrict__ L, h16x8* __restrict__ AhSw,
        signed char* __restrict__ A8r, float* __restrict__ sAg) {
    __shared__ float lds[64][65];
    __shared__ float smax[64];
    const int R0 = (blockIdx.x & 63) * 64;
    const int C0 = (blockIdx.x >> 6) * 64;
    const int tid = threadIdx.x;
    #pragma unroll
    for (int it = 0; it < 16; ++it) {
        const int r = it * 4 + (tid >> 6);
        const int c = tid & 63;
        lds[r][c] = A[(size_t)(R0 + r) * NDIM + C0 + c]
                  - L[R0 + r] * C[C0 + c];
    }
    __syncthreads();
    if (tid < 64) {
        float mx = 0.0f;
        #pragma unroll 8
        for (int c = 0; c < 64; ++c) mx = fmaxf(mx, fabsf(lds[tid][c]));
        smax[tid] = mx;
        sAg[(size_t)(R0 + tid) * 64 + (C0 >> 6)] = mx / 127.0f;
    }
    __syncthreads();
    // int8 emission: thread -> row tid>>2, 16-col segment tid&3
    {
        const int r = tid >> 2, seg = tid & 3;
        const float mx = smax[r];
        const float inv = mx > 0.0f ? 127.0f / mx : 0.0f;
        union { int4 v; signed char c[16]; } uo;
        #pragma unroll
        for (int j = 0; j < 16; ++j) {
            int qv = (int)rintf(lds[r][seg * 16 + j] * inv);
            qv = qv > 127 ? 127 : (qv < -127 ? -127 : qv);
            uo.c[j] = (signed char)qv;
        }
        *(int4*)(A8r + (size_t)(R0 + r) * NDIM + C0 + seg * 16) = uo.v;
    }
    // fp16 frag emission (r12-identical)
    #pragma unroll
    for (int half = 0; half < 2; ++half) {
        const int o = half * 256 + tid;
        const int r = o >> 3;
        const int g = o & 7;
        union { h16x8 v; f16 h[8]; } pk;
        #pragma unroll
        for (int j = 0; j < 8; ++j) pk.h[j] = (f16)lds[r][g * 8 + j];
        const int tile = (R0 >> 4) + (r >> 4);
        const int kc   = (C0 >> 5) + (g >> 2);
        const int lane = (r & 15) | ((g & 3) << 4);
        AhSw[((size_t)tile * KC + kc) * 64 + lane] = pk.v;
    }
}

// ---------- W0 = K = [B-L*D | L | ones | 0-pad], fp16 ----------
__global__ __launch_bounds__(256) void k_build_w0(
        const float* __restrict__ Bm, const float* __restrict__ Dm,
        const float* __restrict__ L, f16* __restrict__ Wh) {
    int k = blockIdx.x * blockDim.x + threadIdx.x; // < 4096
    float Lk = L[k];
    float col[16];
    #pragma unroll
    for (int c = 0; c < 8; ++c) col[c] = Bm[k * 8 + c] - Lk * Dm[c];
    col[8] = Lk; col[9] = 1.0f;
    #pragma unroll
    for (int c = 10; c < 16; ++c) col[c] = 0.0f;
    #pragma unroll
    for (int c = 0; c < 16; ++c) Wh[c * NDIM + k] = (f16)col[c];
}

// ---------- fused step: V-role (blocks 0..127) + R-role (blocks 128..255) --
// V: block tp owns tiles 2tp,2tp+1; wave w: tile 2tp+(w>>1), k-half (w&1);
//    fp16 MFMA, dead-col skip (r6/r12 exact). Epilogue writes Wh only.
// R: block t owns rows [32t,32t+32): reduce 128 fp16 partials, emit g_r,
//    next partials from int8 A8r with per-group scales (gsc staged in LDS).
__global__ __launch_bounds__(256) void k_stepVR(
        const h16x8* __restrict__ AhSw,
        const signed char* __restrict__ A8r, const float* __restrict__ sAg,
        const f16* __restrict__ WhIn, f16* __restrict__ WhOut,
        const float* __restrict__ Cvec,
        const f16* __restrict__ RpartIn, f16* __restrict__ RpartOut,
        float* __restrict__ gfSlot, const int r) {
    const int tid = threadIdx.x;

    if (blockIdx.x < 128) {
        // ---------------- V role ----------------
        __shared__ f32x4 red[4][64];
        const int lane = tid & 63, wave = tid >> 6;
        const int mr   = lane & 15, q = lane >> 4;
        const int tp   = blockIdx.x;
        const int tile = tp * 2 + (wave >> 1);
        const int kh   = wave & 1;
        const int k0   = kh * 2048;
        const bool liveB = (mr < NC);
        const h16x8* a8 = AhSw + ((size_t)tile * KC + (size_t)kh * 64) * 64 + lane;
        const h16x8* b8 = (const h16x8*)WhIn + (((size_t)mr * NDIM + k0) >> 3) + q;

        f32x4 acc0 = {0,0,0,0}, acc1 = {0,0,0,0};
        for (int it = 0; it < 8; ++it) {
            h16x8 ra[8], rb[8];
            #pragma unroll
            for (int s = 0; s < 8; ++s) rb[s] = (h16x8){0,0,0,0,0,0,0,0};
            #pragma unroll
            for (int s = 0; s < 8; ++s) {
                const int c = it * 8 + s;           // kc-local 0..63
                ra[s] = a8[(size_t)c * 64];
            }
            if (liveB) {
                #pragma unroll
                for (int s = 0; s < 8; ++s) {
                    const int c = it * 8 + s;
                    rb[s] = b8[c * 4];
                }
            }
            #pragma unroll
            for (int s = 0; s < 8; ++s) {
                if (s & 1) acc1 = __builtin_amdgcn_mfma_f32_16x16x32_f16(ra[s], rb[s], acc1, 0, 0, 0);
                else       acc0 = __builtin_amdgcn_mfma_f32_16x16x32_f16(ra[s], rb[s], acc0, 0, 0, 0);
            }
        }
        red[wave][lane] = acc0 + acc1;
        __syncthreads();
        if (tid < 128) {
            const int half = tid >> 6;          // 0: tile 2tp, 1: tile 2tp+1
            const int l    = tid & 63;
            f32x4 v = red[half * 2][l] + red[half * 2 + 1][l];
            const int col = l & 15;
            if (col < NC) {
                const int row0 = (tp * 2 + half) * 16;
                const int rb0  = row0 + ((l >> 4) << 2);
                #pragma unroll
                for (int i = 0; i < 4; ++i)
                    WhOut[col * NDIM + rb0 + i] = (f16)v[i];
            }
        }
    } else {
        // ---------------- R role ----------------
        __shared__ f16   rp[128][32];   // fp16 partials, 8 KB
        __shared__ float g8[8][33];
        __shared__ float gs[32];
        __shared__ float gsc[32][64];   // gs[rr] * sAg[row][g], 8 KB
        const int t = blockIdx.x - 128;  // rows [32t, 32t+32)

        if (r == 0) {
            if (tid < 32) gs[tid] = Cvec[t * 32 + tid];
        } else {
            {
                const int p = tid >> 1, half = tid & 1;
                const h16x8* src = (const h16x8*)(RpartIn
                        + (size_t)p * NDIM + t * 32 + half * 16);
                h16x8 v0 = src[0], v1 = src[1];
                *(h16x8*)&rp[p][half * 16]     = v0;
                *(h16x8*)&rp[p][half * 16 + 8] = v1;
            }
            __syncthreads();
            {
                const int c = tid & 31, g = tid >> 5;   // 8 groups x 32 cols
                float s = 0.0f;
                #pragma unroll
                for (int j = 0; j < 16; ++j) s += (float)rp[g * 16 + j][c];
                g8[g][c] = s;
            }
            __syncthreads();
            if (tid < 32) {
                float s = 0.0f;
                #pragma unroll
                for (int g = 0; g < 8; ++g) s += g8[g][tid];
                gs[tid] = s;
            }
        }
        __syncthreads();
        if (tid < 32) gfSlot[t * 32 + tid] = gs[tid];

        if (r < VAPPS - 1) {
            // stage gs[rr] * sAg[(32t+rr)][g] into LDS
            #pragma unroll
            for (int i = 0; i < 8; ++i) {
                const int idx = tid + i * 256;          // 0..2047
                const int rr = idx >> 6, g = idx & 63;
                gsc[rr][g] = gs[rr] * sAg[(size_t)(t * 32 + rr) * 64 + g];
            }
            __syncthreads();
            const int c0 = tid * 16;            // 16 cols per thread
            const int g0 = tid >> 2;            // col-group (fixed per thread)
            float acc[16] = {};
            const int4* arow = (const int4*)(A8r + (size_t)(t * 32) * NDIM + c0);
            for (int rr = 0; rr < 32; ++rr) {
                const int4 v = arow[(size_t)rr * (NDIM / 16)];
                const float gm = gsc[rr][g0];
                const int w0 = v.x, w1 = v.y, w2 = v.z, w3 = v.w;
                #pragma unroll
                for (int b = 0; b < 4; ++b) {
                    acc[b]      += gm * (float)((w0 << (24 - 8 * b)) >> 24);
                    acc[4 + b]  += gm * (float)((w1 << (24 - 8 * b)) >> 24);
                    acc[8 + b]  += gm * (float)((w2 << (24 - 8 * b)) >> 24);
                    acc[12 + b] += gm * (float)((w3 << (24 - 8 * b)) >> 24);
                }
            }
            union { h16x8 h; int4 i4; } o0, o1;
            #pragma unroll
            for (int j = 0; j < 8; ++j) {
                o0.h[j] = (f16)acc[j];
                o1.h[j] = (f16)acc[8 + j];
            }
            h16x8* op = (h16x8*)(RpartOut + (size_t)t * NDIM + c0);
            op[0] = o0.h;
            op[1] = o1.h;
        }
    }
}

// ---------- f_m for all m: m<=28 via C.W_m, m=28+i via g_i.W_28 ----------
__global__ __launch_bounds__(256) void k_fbatch(
        const f16* __restrict__ Wh, const float* __restrict__ C,
        const float* __restrict__ gf, float* __restrict__ F) {
    const int m = blockIdx.x;             // 0..JT-1
    const f16* W;
    const float* vec;
    if (m <= VAPPS) { W = Wh + (size_t)m * SLAB;     vec = C; }
    else            { W = Wh + (size_t)VAPPS * SLAB; vec = gf + (size_t)(m - VAPPS) * NDIM; }
    const int tid = threadIdx.x, lane = tid & 63, wave = tid >> 6;
    float acc[NC] = {};
    for (int k = tid; k < NDIM; k += 256) {
        float ck = vec[k];
        #pragma unroll
        for (int c = 0; c < NC; ++c) acc[c] += ck * (float)W[c * NDIM + k];
    }
    __shared__ float red[4][NC];
    #pragma unroll
    for (int c = 0; c < NC; ++c) {
        float s = acc[c];
        #pragma unroll
        for (int off = 32; off > 0; off >>= 1) s += __shfl_down(s, off);
        if (lane == 0) red[wave][c] = s;
    }
    __syncthreads();
    if (tid < NC) F[m * NC + tid] = red[0][tid] + red[1][tid] + red[2][tid] + red[3][tid];
}

// ---------- causal convolution + tanh epilogue ----------
__global__ __launch_bounds__(256) void k_conv(
        const float* __restrict__ F, const float* __restrict__ u,
        const float* __restrict__ yobs, const float* __restrict__ Dm,
        float* __restrict__ out) {
    __shared__ float Fl[JT * NC];
    __shared__ float zw[(JT + 256) * 9];
    const int tid = threadIdx.x;
    const int t0  = blockIdx.x * 256;
    for (int idx = tid; idx < JT * NC; idx += 256) Fl[idx] = F[idx];
    for (int idx = tid; idx < (JT + 256) * 9; idx += 256) {
        int k = idx / 9, c = idx - k * 9;
        int s = t0 - JT + k;
        float v = 0.0f;
        if (s >= 0 && s < NDIM) v = (c < 8) ? u[c * NDIM + s] : yobs[s];
        zw[idx] = v;
    }
    __syncthreads();
    const int t = t0 + tid;
    float y = (t < JT) ? Fl[t * NC + 9] : 0.0f; // C A'^t h0 term (truncated)
    #pragma unroll
    for (int c = 0; c < 8; ++c) y += Dm[c] * u[c * NDIM + t];
    for (int j = 0; j < JT; ++j) { // s = t-1-j; s<0 hits zero pad
        const float* fj = Fl + j * NC;
        const float* zz = zw + (tid + JT - 1 - j) * 9;
        float p = 0.0f;
        #pragma unroll
        for (int c = 0; c < 9; ++c) p += fj[c] * zz[c];
        y += p;
    }
    out[t] = 3.0f * tanhf(y);
}

extern "C" void kernel_launch(void* const* d_in, const int* in_sizes, int n_in,
                              void* d_out, int out_size, void* d_ws, size_t ws_size,
                              hipStream_t stream) {
    const float* u    = (const float*)d_in[0];
    const float* yobs = (const float*)d_in[1];
    const float* A    = (const float*)d_in[2];
    const float* Bm   = (const float*)d_in[3];
    const float* C    = (const float*)d_in[4];
    const float* Dm   = (const float*)d_in[5];
    const float* L    = (const float*)d_in[6];
    float* out = (float*)d_out;

    // workspace layout (~58 MB)
    char* ws = (char*)d_ws;
    h16x8*       AhSw  = (h16x8*)ws;                        // 32 MB
    signed char* A8r   = (signed char*)(ws + 33554432ull);  // 16 MB
    float*       sAg   = (float*)(ws + 50331648ull);        // 1 MB (4096x64)
    f16*         Wh    = (f16*)(ws + 51380224ull);          // 29*128 KB
    float*       gf    = (float*)(ws + 55181312ull);        // 28*16 KB
    f16*         RpartH= (f16*)(ws + 55640064ull);          // 2*1 MB (ping-pong)
    float*       F     = (float*)(ws + 57737216ull);        // 2.24 KB

    constexpr size_t RPN = (size_t)128 * NDIM;   // one Rpart buffer (f16 elems)

    k_build_w0<<<dim3(16), dim3(256), 0, stream>>>(Bm, Dm, L, Wh);
    k_build_a<<<dim3(64 * 64), dim3(256), 0, stream>>>(A, C, L, AhSw, A8r, sAg);

    for (int r = 0; r < VAPPS; ++r) {
        const size_t in   = (size_t)r * SLAB;
        const size_t out_ = (size_t)(r + 1) * SLAB;
        const f16* rin  = RpartH + ((r + 1) & 1) * RPN;
        f16*       rout = RpartH + (r & 1) * RPN;
        k_stepVR<<<dim3(256), dim3(256), 0, stream>>>(
            AhSw, A8r, sAg, Wh + in, Wh + out_,
            C, rin, rout, gf + (size_t)r * NDIM, r);
    }

    k_fbatch<<<dim3(JT), dim3(256), 0, stream>>>(Wh, C, gf, F);
    k_conv<<<dim3(16), dim3(256), 0, stream>>>(F, u, yobs, Dm, out);
}